// Round 5
// baseline (5145.673 us; speedup 1.0000x reference)
//
#include <hip/hip_runtime.h>

// Critic_Net pointer-network forward. fp32 state/accumulate, fp16 weights +
// fp16 activations + v_dot2_f32_f16 (R4), + register-resident recurrent
// weights (Whh in k_process, EWhh in k_encoder) and merged glimpse phase (R5).

constexpr int kH = 128, kE = 128, kD = 256, kB = 512, kT = 100, kG = 512, kMID = 100;

typedef _Float16 half2_t __attribute__((ext_vector_type(2)));

// ws layout (float units)
constexpr size_t WS_ENCH  = 0;                                 // half[B][T][D]
constexpr size_t WS_REFTH = WS_ENCH  + (size_t)kB * kT * kD/2; // half[B][D][T]
constexpr size_t WS_EW2   = WS_REFTH + (size_t)kB * kD * kT/2; // half2[2][64][512]  (65,536 f)
constexpr size_t WS_ECG   = WS_EW2   + 65536;                  // f32 [2][512][4]
constexpr size_t WS_PW2   = WS_ECG   + 4096;                   // half2[192][1024]   (196,608 f)
constexpr size_t WS_PB    = WS_PW2   + 196608;                 // f32 [1024]
constexpr size_t WS_WQ2   = WS_PB    + 1024;                   // half2[128][256]    (32,768 f)
constexpr size_t WS_WREFT = WS_WQ2   + 32768;                  // f32 [D][D]
constexpr size_t WS_HST   = WS_WREFT + (size_t)kD * kD;        // f32 [4][B][H]
constexpr size_t WS_POUT  = WS_HST   + (size_t)4 * kB * kH;    // f32 [B][D]

__device__ __forceinline__ float rcpf(float x) { return __builtin_amdgcn_rcpf(x); }
__device__ __forceinline__ float sigf(float x) { return rcpf(1.0f + __expf(-x)); }
__device__ __forceinline__ float tanhf_(float x) {
    float t = __expf(2.0f * x);            // inf-safe: rcp(inf)=0 -> 1; t->0 -> -1
    return 1.0f - 2.0f * rcpf(1.0f + t);
}
__device__ __forceinline__ float fdot2(half2_t a, half2_t b, float c) {
#if __has_builtin(__builtin_amdgcn_fdot2)
    return __builtin_amdgcn_fdot2(a, b, c, false);
#else
    return c + (float)a.x * (float)b.x + (float)a.y * (float)b.y;
#endif
}

// ---------------- prep: encoder input coefficients ----------------
__global__ void k_prep_ec(const float* __restrict__ Wih_f, const float* __restrict__ Wih_b,
                          const float* __restrict__ b_f, const float* __restrict__ b_b,
                          const float* __restrict__ Wemb, float* __restrict__ ws) {
    int id = blockIdx.x * 256 + threadIdx.x;   // 0..1023 : (dir, j)
    int dir = id >> 9, j = id & 511;
    const float* Wih = dir ? Wih_b : Wih_f;
    const float* bb  = dir ? b_b   : b_f;
    float c0 = 0.f, c1 = 0.f;
    for (int e = 0; e < kE; ++e) {
        float w = Wih[j * kE + e];
        c0 += w * Wemb[e * 2 + 0];
        c1 += w * Wemb[e * 2 + 1];
    }
    float* ecg = ws + WS_ECG + (size_t)id * 4;
    ecg[0] = c0; ecg[1] = c1; ecg[2] = bb[j]; ecg[3] = 0.f;
}

// ---------------- prep: weight transposes / k-pair half2 packing ----------------
__global__ void k_prep_tr(const float* __restrict__ eWhh_f, const float* __restrict__ eWhh_b,
                          const float* __restrict__ pWih_f, const float* __restrict__ pWih_b,
                          const float* __restrict__ pWhh_f, const float* __restrict__ pWhh_b,
                          const float* __restrict__ pb_f, const float* __restrict__ pb_b,
                          const float* __restrict__ Wq, const float* __restrict__ Wref,
                          float* __restrict__ ws) {
    int id = blockIdx.x * 256 + threadIdx.x;   // exactly 361,472 threads
    if (id < 65536) {                          // EW2 half2[2][64][512]: {W[j][2kp],W[j][2kp+1]}
        int dir = id >> 15, rem = id & 32767, kp = rem >> 9, j = rem & 511;
        const float* W = dir ? eWhh_b : eWhh_f;
        half2_t v = {(_Float16)W[j * kH + 2 * kp], (_Float16)W[j * kH + 2 * kp + 1]};
        ((half2_t*)(ws + WS_EW2))[id] = v;
        return;
    }
    id -= 65536;
    if (id < 196608) {                         // PW2 half2[192][1024]
        int kp = id >> 10, j = id & 1023;
        int k0 = 2 * kp, k1 = 2 * kp + 1;
        float a, b;
        if (k0 < 256) {
            a = (j < 512) ? pWih_f[j * kD + k0] : pWih_b[(j - 512) * kD + k0];
            b = (j < 512) ? pWih_f[j * kD + k1] : pWih_b[(j - 512) * kD + k1];
        } else {
            a = (j < 512) ? pWhh_f[j * kH + (k0 - 256)] : pWhh_b[(j - 512) * kH + (k0 - 256)];
            b = (j < 512) ? pWhh_f[j * kH + (k1 - 256)] : pWhh_b[(j - 512) * kH + (k1 - 256)];
        }
        half2_t v = {(_Float16)a, (_Float16)b};
        ((half2_t*)(ws + WS_PW2))[id] = v;
        return;
    }
    id -= 196608;
    if (id < 1024) {                           // PB [1024] fp32
        ws[WS_PB + id] = (id < 512) ? pb_f[id] : pb_b[id - 512];
        return;
    }
    id -= 1024;
    if (id < 32768) {                          // WQ2 half2[128][256]: {Wq[n][2kp],Wq[n][2kp+1]}
        int kp = id >> 8, n = id & 255;
        half2_t v = {(_Float16)Wq[n * kD + 2 * kp], (_Float16)Wq[n * kD + 2 * kp + 1]};
        ((half2_t*)(ws + WS_WQ2))[id] = v;
        return;
    }
    id -= 32768;
    if (id < 65536) {                          // WrefT [256][256] fp32
        int k = id >> 8, n = id & 255;
        ws[WS_WREFT + id] = Wref[n * kD + k];
        return;
    }
}

// ---------------- encoder: bidir LSTM, 4 rows/block, weights in VGPRs ----------------
__global__ __launch_bounds__(512, 2) void k_encoder(const float* __restrict__ inp,
                                                    float* __restrict__ ws) {
    const int dir = blockIdx.x & 1;
    const int b0  = (blockIdx.x >> 1) * 4;
    const int tid = threadIdx.x;
    const int jq  = tid & 127;                 // j4 = 4*jq
    const int kg  = tid >> 7;                  // 0..3, 16 kp each
    __shared__ __align__(16) half2_t shT2[64][4];       // h pairs [kp][r] (1KB)
    __shared__ float scs[4][kH];                        // c state
    __shared__ __align__(16) float uniE[4 * 4 * 512];   // partials [kg][r][j] (32KB)
    __shared__ __align__(16) float4 secg[512];          // input coeffs per j (8KB)
    __shared__ float sx[4][2];
    if (tid < 256) ((float*)shT2)[tid] = 0.f;
    if (tid < 512) scs[tid >> 7][tid & 127] = 0.f;
    secg[tid] = *(const float4*)(ws + WS_ECG + (size_t)(dir * 512 + tid) * 4);
    const float4* EW2f4 = (const float4*)(ws + WS_EW2) + (size_t)dir * 64 * 128; // [64][128]
    _Float16* ench = (_Float16*)(ws + WS_ENCH);
    float* hst = ws + WS_HST;
    float4* uniE4 = (float4*)uniE;
    // one-time: this thread's 16-kp weight slice into registers (64 VGPR)
    float4 wregE[16];
    #pragma unroll
    for (int i = 0; i < 16; ++i) wregE[i] = EW2f4[(kg * 16 + i) * 128 + jq];
    __syncthreads();
    for (int s = 0; s < kT; ++s) {
        const int t = dir ? (kT - 1 - s) : s;
        if (tid < 8) { int r = tid >> 1, c = tid & 1; sx[r][c] = inp[((size_t)(b0 + r) * kT + t) * 2 + c]; }
        {   // partial gates: (jq, kg): 16 kp, 4 rows, 4 j — all weights in regs
            float aa[16];
            #pragma unroll
            for (int i = 0; i < 16; ++i) aa[i] = 0.f;
            #pragma unroll
            for (int kk = 0; kk < 16; ++kk) {
                int kp = kg * 16 + kk;
                float4 xraw = *(const float4*)&shT2[kp][0];
                const half2_t* wp = (const half2_t*)&wregE[kk];
                const half2_t* xp = (const half2_t*)&xraw;
                #pragma unroll
                for (int j = 0; j < 4; ++j)
                    #pragma unroll
                    for (int r = 0; r < 4; ++r)
                        aa[j * 4 + r] = fdot2(wp[j], xp[r], aa[j * 4 + r]);
            }
            #pragma unroll
            for (int r = 0; r < 4; ++r)
                uniE4[(kg * 4 + r) * 128 + jq] = make_float4(aa[0*4+r], aa[1*4+r], aa[2*4+r], aa[3*4+r]);
        }
        __syncthreads();
        {   // cell with fused reduce: (r, k)
            const int r = tid >> 7, k = tid & 127;
            float4 c0 = secg[k], c1 = secg[128 + k], c2 = secg[256 + k], c3 = secg[384 + k];
            float x0 = sx[r][0], x1 = sx[r][1];
            float gi = c0.z + x0 * c0.x + x1 * c0.y;
            float gf = c1.z + x0 * c1.x + x1 * c1.y;
            float gg = c2.z + x0 * c2.x + x1 * c2.y;
            float go = c3.z + x0 * c3.x + x1 * c3.y;
            #pragma unroll
            for (int g4 = 0; g4 < 4; ++g4) {
                const float* u = &uniE[(g4 * 4 + r) * 512];
                gi += u[k]; gf += u[k + 128]; gg += u[k + 256]; go += u[k + 384];
            }
            float cc = sigf(gf) * scs[r][k] + sigf(gi) * tanhf_(gg);
            float hh = sigf(go) * tanhf_(cc);
            scs[r][k] = cc;
            ((_Float16*)shT2)[((k >> 1) * 4 + r) * 2 + (k & 1)] = (_Float16)hh;
            ench[((size_t)(b0 + r) * kT + t) * kD + dir * kH + k] = (_Float16)hh;
            if (s == kT - 1) {
                hst[(size_t)(dir * 2 + 0) * kB * kH + (size_t)(b0 + r) * kH + k] = hh;
                hst[(size_t)(dir * 2 + 1) * kB * kH + (size_t)(b0 + r) * kH + k] = cc;
            }
        }
        __syncthreads();
    }
}

// ---------------- ref = enc @ W_ref.T -> refTh fp16 [B][D][T] ----------------
__global__ __launch_bounds__(256) void k_refgemm(float* __restrict__ ws) {
    const int tid = threadIdx.x;
    const int m0 = blockIdx.x * 20;            // 20 bt-rows, within one b
    const int b = m0 / kT, t0 = m0 % kT;
    __shared__ float se[20][kD];
    __shared__ float so[20][257];
    const _Float16* ench = (const _Float16*)(ws + WS_ENCH);
    const float* WrT = ws + WS_WREFT;
    _Float16* refTh = (_Float16*)(ws + WS_REFTH);
    #pragma unroll
    for (int i = 0; i < 20; ++i) se[i][tid] = (float)ench[(size_t)(m0 + i) * kD + tid];
    __syncthreads();
    float acc[20];
    #pragma unroll
    for (int r = 0; r < 20; ++r) acc[r] = 0.f;
    #pragma unroll 2
    for (int k = 0; k < kD; ++k) {
        float w = WrT[k * kD + tid];
        #pragma unroll
        for (int r = 0; r < 20; ++r) acc[r] += se[r][k] * w;
    }
    #pragma unroll
    for (int r = 0; r < 20; ++r) so[r][tid] = acc[r];
    __syncthreads();
    #pragma unroll
    for (int i = 0; i < 20; ++i) {
        int idx = i * 256 + tid;
        int d = idx / 20, tt = idx - d * 20;
        refTh[(size_t)b * kD * kT + d * kT + t0 + tt] = (_Float16)so[tt][d];
    }
}

// ---------------- process: 100-step pointer loop, 2 rows per block ----------------
__global__ __launch_bounds__(1024, 4) void k_process(const float* __restrict__ vw,
                                                     const float* __restrict__ vb,
                                                     float* __restrict__ ws) {
    const int tid = threadIdx.x;
    const int b0 = blockIdx.x * 2;
    // xh2[jh][kp][r]: kp<128 = pin pairs (dup across jh); kp in [128,192) = h(dir=jh) pairs
    __shared__ __align__(16) half2_t xh2[2][192][2];    // 3KB
    __shared__ float pc[2][2][kH];                      // c state [dir][r][k]
    __shared__ float hfp[2][2][kH];                     // h fp32 [dir][r][k]
    __shared__ __align__(16) float uni[8192];           // 32KB scratch
    __shared__ float qv[2][kD];
    __shared__ float at[2][128];
    __shared__ float vwS[kD];
    __shared__ float sbias[1024];
    const float* PB   = ws + WS_PB;
    const _Float16* refTh = (const _Float16*)(ws + WS_REFTH);
    const _Float16* ench  = (const _Float16*)(ws + WS_ENCH);
    const float* hst  = ws + WS_HST;
    const float4* PW2f4 = (const float4*)(ws + WS_PW2); // [192][256] float4
    const float*  WQ2f  = ws + WS_WQ2;                  // [128][256] half2-as-float
    _Float16* xf = (_Float16*)xh2;
    // init
    if (tid < 512) {                           // zero pin region: (jh, kp<128, r)
        int zjh = tid >> 8, zkp = (tid >> 1) & 127, zr = tid & 1;
        ((float*)xh2)[(zjh * 192 + zkp) * 2 + zr] = 0.f;
    }
    if (tid < 512) {                           // states: (r, dir, k)
        int r = tid >> 8, dirk = tid & 255, dir = dirk >> 7, k = dirk & 127;
        float hv = hst[(size_t)(dir * 2 + 0) * kB * kH + (size_t)(b0 + r) * kH + k];
        pc[dir][r][k]  = hst[(size_t)(dir * 2 + 1) * kB * kH + (size_t)(b0 + r) * kH + k];
        hfp[dir][r][k] = hv;
        xf[((dir * 192 + 128 + (k >> 1)) * 2 + r) * 2 + (k & 1)] = (_Float16)hv;
    }
    if (tid < kD) vwS[tid] = vw[tid];
    sbias[tid] = PB[tid];
    const float vbias = vb[0];
    const int jq = tid & 255;                  // j4 = 4*jq
    const int kg = tid >> 8;                   // 0..3
    const int jh = (jq >= 128);
    float4* uni4 = (float4*)uni;
    // one-time: this thread's Whh slice (kp in [128+kg*16, 128+kg*16+16)) -> 64 VGPR
    float4 wreg[16];
    #pragma unroll
    for (int i = 0; i < 16; ++i)
        wreg[i] = PW2f4[(size_t)(128 + kg * 16 + i) * 256 + jq];
    __syncthreads();

    for (int step = 0; step < kT; ++step) {
        {   // P1 gates partial: (jq, kg): stream 32 Wih kp + 16 reg Whh kp; 2 rows x 4 j
            float a00=0,a01=0,a02=0,a03=0, a10=0,a11=0,a12=0,a13=0;
            #pragma unroll 8
            for (int kk = 0; kk < 32; ++kk) {
                int kp = kg * 32 + kk;
                float4 wraw = PW2f4[(size_t)kp * 256 + jq];
                float2 xraw = *(const float2*)&xh2[jh][kp][0];
                const half2_t* wp = (const half2_t*)&wraw;
                const half2_t* xp = (const half2_t*)&xraw;
                a00 = fdot2(wp[0], xp[0], a00); a01 = fdot2(wp[1], xp[0], a01);
                a02 = fdot2(wp[2], xp[0], a02); a03 = fdot2(wp[3], xp[0], a03);
                a10 = fdot2(wp[0], xp[1], a10); a11 = fdot2(wp[1], xp[1], a11);
                a12 = fdot2(wp[2], xp[1], a12); a13 = fdot2(wp[3], xp[1], a13);
            }
            #pragma unroll
            for (int i = 0; i < 16; ++i) {
                int kp = 128 + kg * 16 + i;
                float2 xraw = *(const float2*)&xh2[jh][kp][0];
                const half2_t* wp = (const half2_t*)&wreg[i];
                const half2_t* xp = (const half2_t*)&xraw;
                a00 = fdot2(wp[0], xp[0], a00); a01 = fdot2(wp[1], xp[0], a01);
                a02 = fdot2(wp[2], xp[0], a02); a03 = fdot2(wp[3], xp[0], a03);
                a10 = fdot2(wp[0], xp[1], a10); a11 = fdot2(wp[1], xp[1], a11);
                a12 = fdot2(wp[2], xp[1], a12); a13 = fdot2(wp[3], xp[1], a13);
            }
            uni4[(kg * 2 + 0) * 256 + jq] = make_float4(a00,a01,a02,a03);
            uni4[(kg * 2 + 1) * 256 + jq] = make_float4(a10,a11,a12,a13);
        }
        __syncthreads();
        if (tid < 512) {                       // P2 cells with fused reduce: (r, dir, k)
            int r = tid >> 8, dirk = tid & 255, dir = dirk >> 7, k = dirk & 127;
            int base = dir * 512;
            int j0 = base + k, j1 = base + 128 + k, j2 = base + 256 + k, j3 = base + 384 + k;
            float gi = sbias[j0], gf = sbias[j1], gg = sbias[j2], go = sbias[j3];
            #pragma unroll
            for (int g4 = 0; g4 < 4; ++g4) {
                const float* u = &uni[(g4 * 2 + r) * 1024];
                gi += u[j0]; gf += u[j1]; gg += u[j2]; go += u[j3];
            }
            float cc = sigf(gf) * pc[dir][r][k] + sigf(gi) * tanhf_(gg);
            float hh = sigf(go) * tanhf_(cc);
            pc[dir][r][k] = cc; hfp[dir][r][k] = hh;
            xf[((dir * 192 + 128 + (k >> 1)) * 2 + r) * 2 + (k & 1)] = (_Float16)hh;
        }
        __syncthreads();
        if (step < kT - 1) {
            {   // P4 q partial: (n = tid&255, kh = tid>>8): 32 kp, both rows, fdot2
                int n = tid & 255, kh = tid >> 8;
                float q0 = 0.f, q1 = 0.f;
                #pragma unroll 8
                for (int i = 0; i < 32; ++i) {
                    int kp = kh * 32 + i;
                    int dir = kp >> 6, lkp = kp & 63;
                    float wr = WQ2f[kp * 256 + n];
                    float2 xraw = *(const float2*)&xh2[dir][128 + lkp][0];
                    const half2_t* xp = (const half2_t*)&xraw;
                    half2_t w = *(const half2_t*)&wr;
                    q0 = fdot2(w, xp[0], q0);
                    q1 = fdot2(w, xp[1], q1);
                }
                uni[(kh * 2 + 0) * 256 + n] = q0;
                uni[(kh * 2 + 1) * 256 + n] = q1;
            }
            __syncthreads();
            if (tid < 512) {                   // P5 q reduce
                int r = tid >> 8, n = tid & 255;
                float q = 0.f;
                #pragma unroll
                for (int kh = 0; kh < 4; ++kh) q += uni[(kh * 2 + r) * 256 + n];
                qv[r][n] = q;
            }
            __syncthreads();
            if (tid < 800) {                   // P6 scores partial: (r, dg, t), 64 d each
                int r = tid / 400, rem = tid - r * 400;
                int dg = rem / 100, t = rem - dg * 100;
                const _Float16* rrow = refTh + ((size_t)(b0 + r) * kD + dg * 64) * kT + t;
                float acc = 0.f;
                #pragma unroll 8
                for (int i = 0; i < 64; ++i) {
                    int d = dg * 64 + i;
                    float rv = (float)rrow[(size_t)i * kT];
                    acc += vwS[d] * tanhf_(rv + qv[r][d]);
                }
                uni[(r * 4 + dg) * 100 + t] = acc;
            }
            __syncthreads();
            {   // P7 softmax over t: wave r (r<2)
                int wv = tid >> 6, l = tid & 63;
                if (wv < 2) {
                    int r = wv;
                    float s1 = vbias + uni[(r*4+0)*100 + l] + uni[(r*4+1)*100 + l]
                                     + uni[(r*4+2)*100 + l] + uni[(r*4+3)*100 + l];
                    float s2 = -3.0e38f;
                    if (l + 64 < kT)
                        s2 = vbias + uni[(r*4+0)*100 + l+64] + uni[(r*4+1)*100 + l+64]
                                   + uni[(r*4+2)*100 + l+64] + uni[(r*4+3)*100 + l+64];
                    float m = fmaxf(s1, s2);
                    #pragma unroll
                    for (int off = 32; off > 0; off >>= 1) m = fmaxf(m, __shfl_xor(m, off));
                    float e1 = __expf(s1 - m);
                    float e2 = (l + 64 < kT) ? __expf(s2 - m) : 0.f;
                    float ssum = e1 + e2;
                    #pragma unroll
                    for (int off = 32; off > 0; off >>= 1) ssum += __shfl_xor(ssum, off);
                    float inv = rcpf(ssum);
                    at[r][l] = e1 * inv;
                    at[r][l + 64] = e2 * inv;
                }
            }
            __syncthreads();
            if (tid < 512) {                   // P8 full glimpse: (r, d) -> pin fp16 both copies
                int r = tid >> 8, d = tid & 255;
                const _Float16* erow = ench + (size_t)(b0 + r) * kT * kD + d;
                float acc = 0.f;
                #pragma unroll 4
                for (int t = 0; t < kT; ++t)
                    acc += at[r][t] * (float)erow[(size_t)t * kD];
                _Float16 hv = (_Float16)acc;
                xf[((0 * 192 + (d >> 1)) * 2 + r) * 2 + (d & 1)] = hv;
                xf[((1 * 192 + (d >> 1)) * 2 + r) * 2 + (d & 1)] = hv;
            }
            __syncthreads();
        }
    }
    // write final pout = [hf | hb] (fp32 state)
    float* pout = ws + WS_POUT;
    if (tid < 512) {
        int r = tid >> 8, d = tid & 255;
        pout[(size_t)(b0 + r) * kD + d] = (d < 128) ? hfp[0][r][d] : hfp[1][r][d - 128];
    }
}

// ---------------- final MLP head ----------------
__global__ __launch_bounds__(128) void k_mlp(const float* __restrict__ W1, const float* __restrict__ b1,
                                             const float* __restrict__ W2, const float* __restrict__ b2,
                                             const float* __restrict__ ws, float* __restrict__ out) {
    const int tid = threadIdx.x;
    const int b0 = blockIdx.x * 4;
    __shared__ float sp[4][kD];
    __shared__ float hid[4][kMID];
    const float* pout = ws + WS_POUT;
    #pragma unroll
    for (int i = 0; i < 8; ++i) {
        int f = i * 128 + tid;
        int r = f >> 8, k = f & 255;
        sp[r][k] = pout[(size_t)(b0 + r) * kD + k];
    }
    __syncthreads();
    if (tid < kMID) {
        int m = tid;
        #pragma unroll
        for (int r = 0; r < 4; ++r) {
            float acc = b1[m];
            for (int k = 0; k < kD; ++k) acc += sp[r][k] * W1[m * kD + k];
            hid[r][m] = fmaxf(acc, 0.f);
        }
    }
    __syncthreads();
    if (tid < 4) {
        float acc = b2[0];
        for (int m = 0; m < kMID; ++m) acc += hid[tid][m] * W2[m];
        out[b0 + tid] = acc;
    }
}

extern "C" void kernel_launch(void* const* d_in, const int* in_sizes, int n_in,
                              void* d_out, int out_size, void* d_ws, size_t ws_size,
                              hipStream_t stream) {
    (void)in_sizes; (void)n_in; (void)out_size; (void)ws_size;
    const float* inp    = (const float*)d_in[0];
    const float* Wemb   = (const float*)d_in[1];
    const float* eWih_f = (const float*)d_in[2];
    const float* eWhh_f = (const float*)d_in[3];
    const float* eb_f   = (const float*)d_in[4];
    const float* eWih_b = (const float*)d_in[5];
    const float* eWhh_b = (const float*)d_in[6];
    const float* eb_b   = (const float*)d_in[7];
    const float* Wref   = (const float*)d_in[8];
    const float* Wq     = (const float*)d_in[9];
    const float* vw     = (const float*)d_in[10];
    const float* vb     = (const float*)d_in[11];
    const float* pWih_f = (const float*)d_in[12];
    const float* pWhh_f = (const float*)d_in[13];
    const float* pb_f   = (const float*)d_in[14];
    const float* pWih_b = (const float*)d_in[15];
    const float* pWhh_b = (const float*)d_in[16];
    const float* pb_b   = (const float*)d_in[17];
    const float* W1     = (const float*)d_in[18];
    const float* b1     = (const float*)d_in[19];
    const float* W2     = (const float*)d_in[20];
    const float* b2     = (const float*)d_in[21];
    float* ws  = (float*)d_ws;
    float* out = (float*)d_out;

    k_prep_ec<<<4, 256, 0, stream>>>(eWih_f, eWih_b, eb_f, eb_b, Wemb, ws);
    k_prep_tr<<<1412, 256, 0, stream>>>(eWhh_f, eWhh_b, pWih_f, pWih_b,
                                        pWhh_f, pWhh_b, pb_f, pb_b, Wq, Wref, ws);
    k_encoder<<<256, 512, 0, stream>>>(inp, ws);
    k_refgemm<<<2560, 256, 0, stream>>>(ws);
    k_process<<<256, 1024, 0, stream>>>(vw, vb, ws);
    k_mlp<<<128, 128, 0, stream>>>(W1, b1, W2, b2, ws, out);
}

// Round 6
// 2158.149 us; speedup vs baseline: 2.3843x; 2.3843x over previous
//
#include <hip/hip_runtime.h>

// Critic_Net pointer-network forward. fp32 state/accumulate, fp16 weights +
// fp16 activations + v_dot2_f32_f16 (R4 structure). R6: reverted the R5
// register-resident-Whh spill in k_process (VGPR cap forced scratch spill,
// WRITE_SIZE 512K->17.9M, 2.5x slower); kept encoder reg-weights (small loop
// body, no spill); P6 now loads refT as half2 t-pairs (half the load instrs).

constexpr int kH = 128, kE = 128, kD = 256, kB = 512, kT = 100, kG = 512, kMID = 100;

typedef _Float16 half2_t __attribute__((ext_vector_type(2)));

// ws layout (float units)
constexpr size_t WS_ENCH  = 0;                                 // half[B][T][D]
constexpr size_t WS_REFTH = WS_ENCH  + (size_t)kB * kT * kD/2; // half[B][D][T]
constexpr size_t WS_EW2   = WS_REFTH + (size_t)kB * kD * kT/2; // half2[2][64][512]  (65,536 f)
constexpr size_t WS_ECG   = WS_EW2   + 65536;                  // f32 [2][512][4]
constexpr size_t WS_PW2   = WS_ECG   + 4096;                   // half2[192][1024]   (196,608 f)
constexpr size_t WS_PB    = WS_PW2   + 196608;                 // f32 [1024]
constexpr size_t WS_WQ2   = WS_PB    + 1024;                   // half2[128][256]    (32,768 f)
constexpr size_t WS_WREFT = WS_WQ2   + 32768;                  // f32 [D][D]
constexpr size_t WS_HST   = WS_WREFT + (size_t)kD * kD;        // f32 [4][B][H]
constexpr size_t WS_POUT  = WS_HST   + (size_t)4 * kB * kH;    // f32 [B][D]

__device__ __forceinline__ float rcpf(float x) { return __builtin_amdgcn_rcpf(x); }
__device__ __forceinline__ float sigf(float x) { return rcpf(1.0f + __expf(-x)); }
__device__ __forceinline__ float tanhf_(float x) {
    float t = __expf(2.0f * x);            // inf-safe: rcp(inf)=0 -> 1; t->0 -> -1
    return 1.0f - 2.0f * rcpf(1.0f + t);
}
__device__ __forceinline__ float fdot2(half2_t a, half2_t b, float c) {
#if __has_builtin(__builtin_amdgcn_fdot2)
    return __builtin_amdgcn_fdot2(a, b, c, false);
#else
    return c + (float)a.x * (float)b.x + (float)a.y * (float)b.y;
#endif
}

// ---------------- prep: encoder input coefficients ----------------
__global__ void k_prep_ec(const float* __restrict__ Wih_f, const float* __restrict__ Wih_b,
                          const float* __restrict__ b_f, const float* __restrict__ b_b,
                          const float* __restrict__ Wemb, float* __restrict__ ws) {
    int id = blockIdx.x * 256 + threadIdx.x;   // 0..1023 : (dir, j)
    int dir = id >> 9, j = id & 511;
    const float* Wih = dir ? Wih_b : Wih_f;
    const float* bb  = dir ? b_b   : b_f;
    float c0 = 0.f, c1 = 0.f;
    for (int e = 0; e < kE; ++e) {
        float w = Wih[j * kE + e];
        c0 += w * Wemb[e * 2 + 0];
        c1 += w * Wemb[e * 2 + 1];
    }
    float* ecg = ws + WS_ECG + (size_t)id * 4;
    ecg[0] = c0; ecg[1] = c1; ecg[2] = bb[j]; ecg[3] = 0.f;
}

// ---------------- prep: weight transposes / k-pair half2 packing ----------------
__global__ void k_prep_tr(const float* __restrict__ eWhh_f, const float* __restrict__ eWhh_b,
                          const float* __restrict__ pWih_f, const float* __restrict__ pWih_b,
                          const float* __restrict__ pWhh_f, const float* __restrict__ pWhh_b,
                          const float* __restrict__ pb_f, const float* __restrict__ pb_b,
                          const float* __restrict__ Wq, const float* __restrict__ Wref,
                          float* __restrict__ ws) {
    int id = blockIdx.x * 256 + threadIdx.x;   // exactly 361,472 threads
    if (id < 65536) {                          // EW2 half2[2][64][512]: {W[j][2kp],W[j][2kp+1]}
        int dir = id >> 15, rem = id & 32767, kp = rem >> 9, j = rem & 511;
        const float* W = dir ? eWhh_b : eWhh_f;
        half2_t v = {(_Float16)W[j * kH + 2 * kp], (_Float16)W[j * kH + 2 * kp + 1]};
        ((half2_t*)(ws + WS_EW2))[id] = v;
        return;
    }
    id -= 65536;
    if (id < 196608) {                         // PW2 half2[192][1024]
        int kp = id >> 10, j = id & 1023;
        int k0 = 2 * kp, k1 = 2 * kp + 1;
        float a, b;
        if (k0 < 256) {
            a = (j < 512) ? pWih_f[j * kD + k0] : pWih_b[(j - 512) * kD + k0];
            b = (j < 512) ? pWih_f[j * kD + k1] : pWih_b[(j - 512) * kD + k1];
        } else {
            a = (j < 512) ? pWhh_f[j * kH + (k0 - 256)] : pWhh_b[(j - 512) * kH + (k0 - 256)];
            b = (j < 512) ? pWhh_f[j * kH + (k1 - 256)] : pWhh_b[(j - 512) * kH + (k1 - 256)];
        }
        half2_t v = {(_Float16)a, (_Float16)b};
        ((half2_t*)(ws + WS_PW2))[id] = v;
        return;
    }
    id -= 196608;
    if (id < 1024) {                           // PB [1024] fp32
        ws[WS_PB + id] = (id < 512) ? pb_f[id] : pb_b[id - 512];
        return;
    }
    id -= 1024;
    if (id < 32768) {                          // WQ2 half2[128][256]: {Wq[n][2kp],Wq[n][2kp+1]}
        int kp = id >> 8, n = id & 255;
        half2_t v = {(_Float16)Wq[n * kD + 2 * kp], (_Float16)Wq[n * kD + 2 * kp + 1]};
        ((half2_t*)(ws + WS_WQ2))[id] = v;
        return;
    }
    id -= 32768;
    if (id < 65536) {                          // WrefT [256][256] fp32
        int k = id >> 8, n = id & 255;
        ws[WS_WREFT + id] = Wref[n * kD + k];
        return;
    }
}

// ---------------- encoder: bidir LSTM, 4 rows/block, weights in VGPRs ----------------
__global__ __launch_bounds__(512, 2) void k_encoder(const float* __restrict__ inp,
                                                    float* __restrict__ ws) {
    const int dir = blockIdx.x & 1;
    const int b0  = (blockIdx.x >> 1) * 4;
    const int tid = threadIdx.x;
    const int jq  = tid & 127;                 // j4 = 4*jq
    const int kg  = tid >> 7;                  // 0..3, 16 kp each
    __shared__ __align__(16) half2_t shT2[64][4];       // h pairs [kp][r] (1KB)
    __shared__ float scs[4][kH];                        // c state
    __shared__ __align__(16) float uniE[4 * 4 * 512];   // partials [kg][r][j] (32KB)
    __shared__ __align__(16) float4 secg[512];          // input coeffs per j (8KB)
    __shared__ float sx[4][2];
    if (tid < 256) ((float*)shT2)[tid] = 0.f;
    if (tid < 512) scs[tid >> 7][tid & 127] = 0.f;
    secg[tid] = *(const float4*)(ws + WS_ECG + (size_t)(dir * 512 + tid) * 4);
    const float4* EW2f4 = (const float4*)(ws + WS_EW2) + (size_t)dir * 64 * 128; // [64][128]
    _Float16* ench = (_Float16*)(ws + WS_ENCH);
    float* hst = ws + WS_HST;
    float4* uniE4 = (float4*)uniE;
    // one-time: this thread's 16-kp weight slice into registers (64 VGPR)
    float4 wregE[16];
    #pragma unroll
    for (int i = 0; i < 16; ++i) wregE[i] = EW2f4[(kg * 16 + i) * 128 + jq];
    __syncthreads();
    for (int s = 0; s < kT; ++s) {
        const int t = dir ? (kT - 1 - s) : s;
        if (tid < 8) { int r = tid >> 1, c = tid & 1; sx[r][c] = inp[((size_t)(b0 + r) * kT + t) * 2 + c]; }
        {   // partial gates: (jq, kg): 16 kp, 4 rows, 4 j — all weights in regs
            float aa[16];
            #pragma unroll
            for (int i = 0; i < 16; ++i) aa[i] = 0.f;
            #pragma unroll
            for (int kk = 0; kk < 16; ++kk) {
                int kp = kg * 16 + kk;
                float4 xraw = *(const float4*)&shT2[kp][0];
                const half2_t* wp = (const half2_t*)&wregE[kk];
                const half2_t* xp = (const half2_t*)&xraw;
                #pragma unroll
                for (int j = 0; j < 4; ++j)
                    #pragma unroll
                    for (int r = 0; r < 4; ++r)
                        aa[j * 4 + r] = fdot2(wp[j], xp[r], aa[j * 4 + r]);
            }
            #pragma unroll
            for (int r = 0; r < 4; ++r)
                uniE4[(kg * 4 + r) * 128 + jq] = make_float4(aa[0*4+r], aa[1*4+r], aa[2*4+r], aa[3*4+r]);
        }
        __syncthreads();
        {   // cell with fused reduce: (r, k)
            const int r = tid >> 7, k = tid & 127;
            float4 c0 = secg[k], c1 = secg[128 + k], c2 = secg[256 + k], c3 = secg[384 + k];
            float x0 = sx[r][0], x1 = sx[r][1];
            float gi = c0.z + x0 * c0.x + x1 * c0.y;
            float gf = c1.z + x0 * c1.x + x1 * c1.y;
            float gg = c2.z + x0 * c2.x + x1 * c2.y;
            float go = c3.z + x0 * c3.x + x1 * c3.y;
            #pragma unroll
            for (int g4 = 0; g4 < 4; ++g4) {
                const float* u = &uniE[(g4 * 4 + r) * 512];
                gi += u[k]; gf += u[k + 128]; gg += u[k + 256]; go += u[k + 384];
            }
            float cc = sigf(gf) * scs[r][k] + sigf(gi) * tanhf_(gg);
            float hh = sigf(go) * tanhf_(cc);
            scs[r][k] = cc;
            ((_Float16*)shT2)[((k >> 1) * 4 + r) * 2 + (k & 1)] = (_Float16)hh;
            ench[((size_t)(b0 + r) * kT + t) * kD + dir * kH + k] = (_Float16)hh;
            if (s == kT - 1) {
                hst[(size_t)(dir * 2 + 0) * kB * kH + (size_t)(b0 + r) * kH + k] = hh;
                hst[(size_t)(dir * 2 + 1) * kB * kH + (size_t)(b0 + r) * kH + k] = cc;
            }
        }
        __syncthreads();
    }
}

// ---------------- ref = enc @ W_ref.T -> refTh fp16 [B][D][T] ----------------
__global__ __launch_bounds__(256) void k_refgemm(float* __restrict__ ws) {
    const int tid = threadIdx.x;
    const int m0 = blockIdx.x * 20;            // 20 bt-rows, within one b
    const int b = m0 / kT, t0 = m0 % kT;
    __shared__ float se[20][kD];
    __shared__ float so[20][257];
    const _Float16* ench = (const _Float16*)(ws + WS_ENCH);
    const float* WrT = ws + WS_WREFT;
    _Float16* refTh = (_Float16*)(ws + WS_REFTH);
    #pragma unroll
    for (int i = 0; i < 20; ++i) se[i][tid] = (float)ench[(size_t)(m0 + i) * kD + tid];
    __syncthreads();
    float acc[20];
    #pragma unroll
    for (int r = 0; r < 20; ++r) acc[r] = 0.f;
    #pragma unroll 2
    for (int k = 0; k < kD; ++k) {
        float w = WrT[k * kD + tid];
        #pragma unroll
        for (int r = 0; r < 20; ++r) acc[r] += se[r][k] * w;
    }
    #pragma unroll
    for (int r = 0; r < 20; ++r) so[r][tid] = acc[r];
    __syncthreads();
    #pragma unroll
    for (int i = 0; i < 20; ++i) {
        int idx = i * 256 + tid;
        int d = idx / 20, tt = idx - d * 20;
        refTh[(size_t)b * kD * kT + d * kT + t0 + tt] = (_Float16)so[tt][d];
    }
}

// ---------------- process: 100-step pointer loop, 2 rows per block ----------------
__global__ __launch_bounds__(1024) void k_process(const float* __restrict__ vw,
                                                  const float* __restrict__ vb,
                                                  float* __restrict__ ws) {
    const int tid = threadIdx.x;
    const int b0 = blockIdx.x * 2;
    // xh2[jh][kp][r]: kp<128 = pin pairs (dup across jh); kp in [128,192) = h(dir=jh) pairs
    __shared__ __align__(16) half2_t xh2[2][192][2];    // 3KB
    __shared__ float pc[2][2][kH];                      // c state [dir][r][k]
    __shared__ float hfp[2][2][kH];                     // h fp32 [dir][r][k]
    __shared__ __align__(16) float uni[8192];           // 32KB scratch
    __shared__ float qv[2][kD];
    __shared__ float at[2][128];
    __shared__ float vwS[kD];
    __shared__ float sbias[1024];
    const float* PB   = ws + WS_PB;
    const _Float16* refTh = (const _Float16*)(ws + WS_REFTH);
    const _Float16* ench  = (const _Float16*)(ws + WS_ENCH);
    const float* hst  = ws + WS_HST;
    const float4* PW2f4 = (const float4*)(ws + WS_PW2); // [192][256] float4
    const float*  WQ2f  = ws + WS_WQ2;                  // [128][256] half2-as-float
    _Float16* xf = (_Float16*)xh2;
    // init
    if (tid < 512) {                           // zero pin region: (jh, kp<128, r)
        int zjh = tid >> 8, zkp = (tid >> 1) & 127, zr = tid & 1;
        ((float*)xh2)[(zjh * 192 + zkp) * 2 + zr] = 0.f;
    }
    if (tid < 512) {                           // states: (r, dir, k)
        int r = tid >> 8, dirk = tid & 255, dir = dirk >> 7, k = dirk & 127;
        float hv = hst[(size_t)(dir * 2 + 0) * kB * kH + (size_t)(b0 + r) * kH + k];
        pc[dir][r][k]  = hst[(size_t)(dir * 2 + 1) * kB * kH + (size_t)(b0 + r) * kH + k];
        hfp[dir][r][k] = hv;
        xf[((dir * 192 + 128 + (k >> 1)) * 2 + r) * 2 + (k & 1)] = (_Float16)hv;
    }
    if (tid < kD) vwS[tid] = vw[tid];
    sbias[tid] = PB[tid];
    const float vbias = vb[0];
    const int jq = tid & 255;                  // j4 = 4*jq
    const int kg = tid >> 8;                   // 0..3, 48 kp each
    const int jh = (jq >= 128);
    float4* uni4 = (float4*)uni;
    __syncthreads();

    for (int step = 0; step < kT; ++step) {
        {   // P1 gates partial: (jq, kg): 48 kp x 2 rows x 4 j, fdot2
            float a00=0,a01=0,a02=0,a03=0, a10=0,a11=0,a12=0,a13=0;
            #pragma unroll 8
            for (int kk = 0; kk < 48; ++kk) {
                int kp = kg * 48 + kk;
                float4 wraw = PW2f4[(size_t)kp * 256 + jq];
                float2 xraw = *(const float2*)&xh2[jh][kp][0];
                const half2_t* wp = (const half2_t*)&wraw;
                const half2_t* xp = (const half2_t*)&xraw;
                a00 = fdot2(wp[0], xp[0], a00); a01 = fdot2(wp[1], xp[0], a01);
                a02 = fdot2(wp[2], xp[0], a02); a03 = fdot2(wp[3], xp[0], a03);
                a10 = fdot2(wp[0], xp[1], a10); a11 = fdot2(wp[1], xp[1], a11);
                a12 = fdot2(wp[2], xp[1], a12); a13 = fdot2(wp[3], xp[1], a13);
            }
            uni4[(kg * 2 + 0) * 256 + jq] = make_float4(a00,a01,a02,a03);
            uni4[(kg * 2 + 1) * 256 + jq] = make_float4(a10,a11,a12,a13);
        }
        __syncthreads();
        if (tid < 512) {                       // P2 cells with fused reduce: (r, dir, k)
            int r = tid >> 8, dirk = tid & 255, dir = dirk >> 7, k = dirk & 127;
            int base = dir * 512;
            int j0 = base + k, j1 = base + 128 + k, j2 = base + 256 + k, j3 = base + 384 + k;
            float gi = sbias[j0], gf = sbias[j1], gg = sbias[j2], go = sbias[j3];
            #pragma unroll
            for (int g4 = 0; g4 < 4; ++g4) {
                const float* u = &uni[(g4 * 2 + r) * 1024];
                gi += u[j0]; gf += u[j1]; gg += u[j2]; go += u[j3];
            }
            float cc = sigf(gf) * pc[dir][r][k] + sigf(gi) * tanhf_(gg);
            float hh = sigf(go) * tanhf_(cc);
            pc[dir][r][k] = cc; hfp[dir][r][k] = hh;
            xf[((dir * 192 + 128 + (k >> 1)) * 2 + r) * 2 + (k & 1)] = (_Float16)hh;
        }
        __syncthreads();
        if (step < kT - 1) {
            {   // P4 q partial: (n = tid&255, kh = tid>>8): 32 kp, both rows, fdot2
                int n = tid & 255, kh = tid >> 8;
                float q0 = 0.f, q1 = 0.f;
                #pragma unroll 8
                for (int i = 0; i < 32; ++i) {
                    int kp = kh * 32 + i;
                    int dir = kp >> 6, lkp = kp & 63;
                    float wr = WQ2f[kp * 256 + n];
                    float2 xraw = *(const float2*)&xh2[dir][128 + lkp][0];
                    const half2_t* xp = (const half2_t*)&xraw;
                    half2_t w = *(const half2_t*)&wr;
                    q0 = fdot2(w, xp[0], q0);
                    q1 = fdot2(w, xp[1], q1);
                }
                uni[(kh * 2 + 0) * 256 + n] = q0;
                uni[(kh * 2 + 1) * 256 + n] = q1;
            }
            __syncthreads();
            if (tid < 512) {                   // P5 q reduce
                int r = tid >> 8, n = tid & 255;
                float q = 0.f;
                #pragma unroll
                for (int kh = 0; kh < 4; ++kh) q += uni[(kh * 2 + r) * 256 + n];
                qv[r][n] = q;
            }
            __syncthreads();
            if (tid < 800) {                   // P6 scores partial: (r, dg8, tp50), 32 d, t-pairs
                int r = tid / 400, rem = tid - r * 400;
                int dg = rem / 50, tp = rem - dg * 50;
                const _Float16* rbase = refTh + ((size_t)(b0 + r) * kD + dg * 32) * kT + 2 * tp;
                float acc0 = 0.f, acc1 = 0.f;
                #pragma unroll 8
                for (int i = 0; i < 32; ++i) {
                    int d = dg * 32 + i;
                    half2_t rv = *(const half2_t*)(rbase + (size_t)i * kT);
                    float qd = qv[r][d], w = vwS[d];
                    acc0 += w * tanhf_((float)rv.x + qd);
                    acc1 += w * tanhf_((float)rv.y + qd);
                }
                uni[(r * 8 + dg) * 100 + 2 * tp]     = acc0;
                uni[(r * 8 + dg) * 100 + 2 * tp + 1] = acc1;
            }
            __syncthreads();
            {   // P7 softmax over t: wave r (r<2), 8 partials
                int wv = tid >> 6, l = tid & 63;
                if (wv < 2) {
                    int r = wv;
                    float s1 = vbias, s2 = -3.0e38f;
                    #pragma unroll
                    for (int g = 0; g < 8; ++g) s1 += uni[(r * 8 + g) * 100 + l];
                    if (l + 64 < kT) {
                        s2 = vbias;
                        #pragma unroll
                        for (int g = 0; g < 8; ++g) s2 += uni[(r * 8 + g) * 100 + l + 64];
                    }
                    float m = fmaxf(s1, s2);
                    #pragma unroll
                    for (int off = 32; off > 0; off >>= 1) m = fmaxf(m, __shfl_xor(m, off));
                    float e1 = __expf(s1 - m);
                    float e2 = (l + 64 < kT) ? __expf(s2 - m) : 0.f;
                    float ssum = e1 + e2;
                    #pragma unroll
                    for (int off = 32; off > 0; off >>= 1) ssum += __shfl_xor(ssum, off);
                    float inv = rcpf(ssum);
                    at[r][l] = e1 * inv;
                    at[r][l + 64] = e2 * inv;
                }
            }
            __syncthreads();
            {   // P8 glimpse partial: (dp = tid&127 -> 2 d, r = bit7, th = tid>>8): 25 t each
                int dp = tid & 127, r = (tid >> 7) & 1, th = tid >> 8;
                const half2_t* erow = (const half2_t*)(ench + ((size_t)(b0 + r) * kT + th * 25) * kD) + dp;
                float a0 = 0.f, a1 = 0.f;
                #pragma unroll 5
                for (int i = 0; i < 25; ++i) {
                    half2_t e = erow[(size_t)i * (kD / 2)];
                    float w = at[r][th * 25 + i];
                    a0 += w * (float)e.x;
                    a1 += w * (float)e.y;
                }
                uni[(th * 2 + r) * 256 + 2 * dp]     = a0;
                uni[(th * 2 + r) * 256 + 2 * dp + 1] = a1;
            }
            __syncthreads();
            if (tid < 512) {                   // P9 glimpse reduce -> pin fp16 (both jh copies)
                int r = tid >> 8, d = tid & 255;
                float v = 0.f;
                #pragma unroll
                for (int th = 0; th < 4; ++th) v += uni[(th * 2 + r) * 256 + d];
                _Float16 hv = (_Float16)v;
                xf[((0 * 192 + (d >> 1)) * 2 + r) * 2 + (d & 1)] = hv;
                xf[((1 * 192 + (d >> 1)) * 2 + r) * 2 + (d & 1)] = hv;
            }
            __syncthreads();
        }
    }
    // write final pout = [hf | hb] (fp32 state)
    float* pout = ws + WS_POUT;
    if (tid < 512) {
        int r = tid >> 8, d = tid & 255;
        pout[(size_t)(b0 + r) * kD + d] = (d < 128) ? hfp[0][r][d] : hfp[1][r][d - 128];
    }
}

// ---------------- final MLP head ----------------
__global__ __launch_bounds__(128) void k_mlp(const float* __restrict__ W1, const float* __restrict__ b1,
                                             const float* __restrict__ W2, const float* __restrict__ b2,
                                             const float* __restrict__ ws, float* __restrict__ out) {
    const int tid = threadIdx.x;
    const int b0 = blockIdx.x * 4;
    __shared__ float sp[4][kD];
    __shared__ float hid[4][kMID];
    const float* pout = ws + WS_POUT;
    #pragma unroll
    for (int i = 0; i < 8; ++i) {
        int f = i * 128 + tid;
        int r = f >> 8, k = f & 255;
        sp[r][k] = pout[(size_t)(b0 + r) * kD + k];
    }
    __syncthreads();
    if (tid < kMID) {
        int m = tid;
        #pragma unroll
        for (int r = 0; r < 4; ++r) {
            float acc = b1[m];
            for (int k = 0; k < kD; ++k) acc += sp[r][k] * W1[m * kD + k];
            hid[r][m] = fmaxf(acc, 0.f);
        }
    }
    __syncthreads();
    if (tid < 4) {
        float acc = b2[0];
        for (int m = 0; m < kMID; ++m) acc += hid[tid][m] * W2[m];
        out[b0 + tid] = acc;
    }
}

extern "C" void kernel_launch(void* const* d_in, const int* in_sizes, int n_in,
                              void* d_out, int out_size, void* d_ws, size_t ws_size,
                              hipStream_t stream) {
    (void)in_sizes; (void)n_in; (void)out_size; (void)ws_size;
    const float* inp    = (const float*)d_in[0];
    const float* Wemb   = (const float*)d_in[1];
    const float* eWih_f = (const float*)d_in[2];
    const float* eWhh_f = (const float*)d_in[3];
    const float* eb_f   = (const float*)d_in[4];
    const float* eWih_b = (const float*)d_in[5];
    const float* eWhh_b = (const float*)d_in[6];
    const float* eb_b   = (const float*)d_in[7];
    const float* Wref   = (const float*)d_in[8];
    const float* Wq     = (const float*)d_in[9];
    const float* vw     = (const float*)d_in[10];
    const float* vb     = (const float*)d_in[11];
    const float* pWih_f = (const float*)d_in[12];
    const float* pWhh_f = (const float*)d_in[13];
    const float* pb_f   = (const float*)d_in[14];
    const float* pWih_b = (const float*)d_in[15];
    const float* pWhh_b = (const float*)d_in[16];
    const float* pb_b   = (const float*)d_in[17];
    const float* W1     = (const float*)d_in[18];
    const float* b1     = (const float*)d_in[19];
    const float* W2     = (const float*)d_in[20];
    const float* b2     = (const float*)d_in[21];
    float* ws  = (float*)d_ws;
    float* out = (float*)d_out;

    k_prep_ec<<<4, 256, 0, stream>>>(eWih_f, eWih_b, eb_f, eb_b, Wemb, ws);
    k_prep_tr<<<1412, 256, 0, stream>>>(eWhh_f, eWhh_b, pWih_f, pWih_b,
                                        pWhh_f, pWhh_b, pb_f, pb_b, Wq, Wref, ws);
    k_encoder<<<256, 512, 0, stream>>>(inp, ws);
    k_refgemm<<<2560, 256, 0, stream>>>(ws);
    k_process<<<256, 1024, 0, stream>>>(vw, vb, ws);
    k_mlp<<<128, 128, 0, stream>>>(W1, b1, W2, b2, ws, out);
}